// Round 13
// baseline (164.790 us; speedup 1.0000x reference)
//
#include <hip/hip_runtime.h>
#include <hip/hip_bf16.h>
#include <math.h>

// Shapes (fixed by the reference)
#define B_SZ   256
#define L_SZ   512
#define FD_SZ  64
#define H1_SZ  512
#define H2_SZ  512
#define G_SZ   32
#define DH_SZ  256
#define M_SZ   (B_SZ * L_SZ)   // 131072 rows

#define ROWS     32            // rows per workgroup
#define H1STRIDE 520           // padded row stride (elements): linear LDS addr

typedef __bf16 bfx8 __attribute__((ext_vector_type(8)));
typedef __bf16 bfx4 __attribute__((ext_vector_type(4)));
typedef float  f32x4 __attribute__((ext_vector_type(4)));
typedef float  f32x16 __attribute__((ext_vector_type(16)));

__device__ __forceinline__ float gelu_exact(float x) {
  return 0.5f * x * (1.0f + erff(x * 0.70710678118654752440f));
}
// tanh-form gelu via sigmoid; log2(e) folded in so v_exp_f32 is used directly.
__device__ __forceinline__ float gelu_fast(float x) {
  float x2 = x * x;
  float w = x * fmaf(0.102943398f, x2, 2.30220931f);
  float e = __builtin_amdgcn_exp2f(-w);
  return x * __builtin_amdgcn_rcpf(1.0f + e);
}
__device__ __forceinline__ float softplus_f(float x) {
  return (x > 20.0f) ? x : log1pf(expf(x));
}
__device__ __forceinline__ __bf16 f2bf(float f) { return (__bf16)f; }

// DPP row_ror:n within each 16-lane row (pure VALU, no LDS pipe).
#define ROR_ADD(x, n)                                                          \
  {                                                                            \
    int _t = __builtin_amdgcn_mov_dpp(__builtin_bit_cast(int, (x)),            \
                                      0x120 + (n), 0xF, 0xF, true);            \
    (x) += __builtin_bit_cast(float, _t);                                      \
  }

#define MFMA16(a, b, c) __builtin_amdgcn_mfma_f32_16x16x32_bf16((a), (b), (c), 0, 0, 0)
#define MFMA32(a, b, c) __builtin_amdgcn_mfma_f32_32x32x16_bf16((a), (b), (c), 0, 0, 0)

// ---------------------------------------------------------------------------
// Repack W1 (64x512) fp32 -> bf16 16x16x32-B-fragment order:
//   block id = mb*2 + ks; lane l holds W1[ks*32+(l>>4)*8+j][16*mb+(l&15)].
// Repack W2 (512x512) fp32 -> bf16 32x32x16-B-fragment order:
//   block id = nb*32 + ks; lane l holds W2[16*ks+(l>>5)*8+j][32*nb+(l&31)].
// Also zeroes `pooled` (512 KB).
// ---------------------------------------------------------------------------
__global__ void repack_kernel(const float* __restrict__ W1,
                              const float* __restrict__ W2,
                              __bf16* __restrict__ W1p,
                              __bf16* __restrict__ W2p,
                              float* __restrict__ pooled) {
  int t = blockIdx.x * 256 + threadIdx.x;
  if (t < 32768)
    *reinterpret_cast<float4*>(pooled + (size_t)t * 4) = (float4){0.f, 0.f, 0.f, 0.f};
  if (t < 4096) {  // W1: 64 blocks * 64 lanes
    int lane = t & 63, blk = t >> 6;
    int ks = blk & 1, mb = blk >> 1;
    int col = 16 * mb + (lane & 15);
    int kbase = ks * 32 + (lane >> 4) * 8;
    bfx8 o;
#pragma unroll
    for (int j = 0; j < 8; ++j) o[j] = f2bf(W1[(size_t)(kbase + j) * H1_SZ + col]);
    *reinterpret_cast<bfx8*>(W1p + (size_t)t * 8) = o;
  } else if (t < 4096 + 32768) {  // W2: 512 blocks * 64 lanes (32x32x16 frags)
    int t2 = t - 4096;
    int lane = t2 & 63, blk = t2 >> 6;
    int ks = blk & 31, nb = blk >> 5;
    int col = 32 * nb + (lane & 31);
    int kbase = 16 * ks + (lane >> 5) * 8;
    bfx8 o;
#pragma unroll
    for (int j = 0; j < 8; ++j) o[j] = f2bf(W2[(size_t)(kbase + j) * H2_SZ + col]);
    *reinterpret_cast<bfx8*>(W2p + (size_t)t2 * 8) = o;
  }
}

// ---------------------------------------------------------------------------
// Fused kernel: 32 rows per workgroup, 1024 threads (16 waves), 8 waves/SIMD.
// Wave w owns 32 h-columns, all 32 rows. Per-wave live set ~52 regs of the
// 64 budget -> ~12 free regs for the explicit 1-deep W2 prefetch.
//  GEMM1 (16x16x32, transposed): h1 cols 32w..32w+31 (mb=2w,2w+1), rows 0..31.
//  GEMM2 (32x32x16): h2 cols 32w..32w+31 (nb=w), rows 0..31, K=512,
//    W2 frag prefetched one ks ahead (rolled loop + peeled tail).
//  Epilogue: butterfly-reduced absorb/atten + pooled.
// LDS: 4K Xs + 33.25K H1s + 4K sl ~= 41.5 KB; occupancy wave-capped at
// 2 blocks/CU = 32 waves/CU.
// ---------------------------------------------------------------------------
__global__ __launch_bounds__(1024, 8) void fused_kernel(
    const float* __restrict__ Xl,
    const __bf16* __restrict__ W1p, const __bf16* __restrict__ W2p,
    const float* __restrict__ b1, const float* __restrict__ b2,
    const float* __restrict__ wa, const float* __restrict__ ba,
    const float* __restrict__ wt, const float* __restrict__ bt,
    float* __restrict__ absorbW, float* __restrict__ attenW,
    float* __restrict__ pooled) {
  __shared__ __bf16 Xs[ROWS * 64];          // 4 KB, 16B-chunk XOR swizzle
  __shared__ __bf16 H1s[ROWS * H1STRIDE];   // 33.25 KB, padded, linear addr
  __shared__ float sl[16 * ROWS * 2];       // 4 KB per-wave partials

  const int tid = threadIdx.x;
  const int lane = tid & 63;
  const int w = tid >> 6;        // wave 0..15
  const int g = lane >> 4;       // k-group 0..3 (16x16x32 frags)
  const int c = lane & 15;       // row/col within 16x16 fragment
  const int c32 = lane & 31;     // col within 32x32 fragment
  const int kg = lane >> 5;      // k-group 0..1 (32x32x16 frags)
  const int R0 = blockIdx.x * ROWS;
  const int bidx = R0 >> 9;      // batch index (tiles aligned within batch)

  // ---- stage Xl tile (32x64 fp32 -> bf16 LDS, swizzled; convert ONCE) ----
  if (tid < 512) {
    int r = tid >> 4;             // 0..31
    int c4 = tid & 15;            // 16 float4 per row
    float4 v = *reinterpret_cast<const float4*>(Xl + (size_t)(R0 + r) * FD_SZ + c4 * 4);
    bfx4 bv;
    bv[0] = f2bf(v.x); bv[1] = f2bf(v.y); bv[2] = f2bf(v.z); bv[3] = f2bf(v.w);
    int chunk = c4 >> 1;          // 8-elem (16B) chunk 0..7
    int off = r * 64 + (((chunk ^ (r & 7)) << 3) + (c4 & 1) * 4);
    *reinterpret_cast<bfx4*>(&Xs[off]) = bv;
  }
  __syncthreads();

  // ---- GEMM1 (transposed): wave computes h1 cols 32w..32w+31, rows 0..31 --
  f32x4 acc1[2][2];
#pragma unroll
  for (int mi = 0; mi < 2; ++mi)
#pragma unroll
    for (int ni = 0; ni < 2; ++ni) acc1[mi][ni] = (f32x4){0.f, 0.f, 0.f, 0.f};

#pragma unroll
  for (int ks = 0; ks < 2; ++ks) {
    bfx8 a1[2];
#pragma unroll
    for (int mi = 0; mi < 2; ++mi) {
      int mb = 2 * w + mi;
      a1[mi] = *reinterpret_cast<const bfx8*>(W1p + ((size_t)(mb * 2 + ks) * 64 + lane) * 8);
    }
    bfx8 bx[2];
#pragma unroll
    for (int ni = 0; ni < 2; ++ni) {
      int r = 16 * ni + c;
      int chunk = ks * 4 + g;
      bx[ni] = *reinterpret_cast<const bfx8*>(&Xs[r * 64 + ((chunk ^ (r & 7)) << 3)]);
    }
#pragma unroll
    for (int mi = 0; mi < 2; ++mi)
#pragma unroll
      for (int ni = 0; ni < 2; ++ni)
        acc1[mi][ni] = MFMA16(a1[mi], bx[ni], acc1[mi][ni]);
  }

  // epilogue GEMM1: bias + gelu -> bf16 -> H1s[row][k], k = 16*mb + 4*g + reg
#pragma unroll
  for (int mi = 0; mi < 2; ++mi) {
    int mb = 2 * w + mi;
    float4 bias4 = *reinterpret_cast<const float4*>(b1 + 16 * mb + 4 * g);
#pragma unroll
    for (int ni = 0; ni < 2; ++ni) {
      int r = 16 * ni + c;                 // x-row (0..31)
      bfx4 pv;
      pv[0] = f2bf(gelu_fast(acc1[mi][ni][0] + bias4.x));
      pv[1] = f2bf(gelu_fast(acc1[mi][ni][1] + bias4.y));
      pv[2] = f2bf(gelu_fast(acc1[mi][ni][2] + bias4.z));
      pv[3] = f2bf(gelu_fast(acc1[mi][ni][3] + bias4.w));
      int off = r * H1STRIDE + 16 * mb + 4 * g;
      *reinterpret_cast<bfx4*>(&H1s[off]) = pv;
    }
  }
  __syncthreads();

  // ---- GEMM2 (32x32x16): wave w owns cols 32w..32w+31 (nb=w), rows 0..31 --
  // W2 fragment prefetched one ks ahead (rolled loop; ~12 free regs).
  f32x16 acc2;   // 16 AGPR
#pragma unroll
  for (int q = 0; q < 16; ++q) acc2[q] = 0.0f;

  const __bf16* wpb = W2p + ((size_t)w * 32 * 64 + lane) * 8;
  const __bf16* h1base = &H1s[c32 * H1STRIDE + 8 * kg];
  bfx8 bw = *reinterpret_cast<const bfx8*>(wpb);
#pragma unroll 1
  for (int ks = 0; ks < 31; ++ks) {
    bfx8 a2 = *reinterpret_cast<const bfx8*>(h1base + ks * 16);
    bfx8 bwn = *reinterpret_cast<const bfx8*>(wpb + (size_t)(ks + 1) * 512);
    __builtin_amdgcn_s_setprio(1);
    acc2 = MFMA32(a2, bw, acc2);
    __builtin_amdgcn_s_setprio(0);
    bw = bwn;
  }
  {  // peeled last iteration (ks = 31)
    bfx8 a2 = *reinterpret_cast<const bfx8*>(h1base + 31 * 16);
    acc2 = MFMA32(a2, bw, acc2);
  }

  // ---- epilogue GEMM2: bias+gelu, butterfly-reduce absorb/atten + pooled ---
  // C layout (32x32): col = lane&31, row = (reg&3) + 8*(reg>>2) + 4*(lane>>5)
  const int col = 32 * w + c32;
  const float b2v = b2[col];
  const float wav = wa[col];
  const float wtv = wt[col];
  float pool0 = 0.0f;
  const int rbase = 4 * kg;
  const bool hi16 = (lane & 16) != 0;

#pragma unroll
  for (int q = 0; q < 8; ++q) {
    int rA = 2 * q, rB = 2 * q + 1;
    float vA = gelu_fast(acc2[rA] + b2v);
    float vB = gelu_fast(acc2[rB] + b2v);
    pool0 += vA + vB;
    float saA = vA * wav, saB = vB * wav;
    float stA = vA * wtv, stB = vB * wtv;
    // 2-for-1 butterfly at the xor16 level, then shared 16-lane DPP tree.
    float zs = hi16 ? saB : saA;
    float ys = hi16 ? saA : saB;
    float zt = hi16 ? stB : stA;
    float yt = hi16 ? stA : stB;
    ys = __shfl_xor(ys, 16, 64);
    yt = __shfl_xor(yt, 16, 64);
    float ss = zs + ys;         // lanes c32<16: rowA partial; >=16: rowB
    float tt = zt + yt;
    ROR_ADD(ss, 8); ROR_ADD(ss, 4); ROR_ADD(ss, 2); ROR_ADD(ss, 1);
    ROR_ADD(tt, 8); ROR_ADD(tt, 4); ROR_ADD(tt, 2); ROR_ADD(tt, 1);
    if (c32 == 0) {
      int row = (rA & 3) + 8 * (rA >> 2) + rbase;
      *reinterpret_cast<float2*>(&sl[w * (2 * ROWS) + row * 2]) = make_float2(ss, tt);
    } else if (c32 == 16) {
      int row = (rB & 3) + 8 * (rB >> 2) + rbase;
      *reinterpret_cast<float2*>(&sl[w * (2 * ROWS) + row * 2]) = make_float2(ss, tt);
    }
  }
  // pooled: col sums need the two lane-halves (row sets) combined
  pool0 += __shfl_xor(pool0, 32, 64);
  if (lane < 32)
    atomicAdd(&pooled[bidx * H2_SZ + col], pool0);
  __syncthreads();

  if (tid < ROWS) {
    float sa = 0.0f, st = 0.0f;
#pragma unroll
    for (int w16 = 0; w16 < 16; ++w16) {
      float2 v2 = *reinterpret_cast<float2*>(&sl[w16 * (2 * ROWS) + tid * 2]);
      sa += v2.x; st += v2.y;
    }
    absorbW[R0 + tid] = softplus_f(sa + ba[0]);
    attenW[R0 + tid]  = softplus_f(st + bt[0]);
  }
}

// ---------------------------------------------------------------------------
// Finalize: per-b reversed exclusive-cumsum scan + captured, pooled head, out
// ---------------------------------------------------------------------------
__global__ __launch_bounds__(256) void finalize_kernel(
    const float* __restrict__ Xg,
    const float* __restrict__ absorbW, const float* __restrict__ attenW,
    const float* __restrict__ pooled,
    const float* __restrict__ Wd1, const float* __restrict__ bd1,
    const float* __restrict__ Wd2, const float* __restrict__ bd2,
    float* __restrict__ out) {
  __shared__ float s0[512];
  __shared__ float s1[512];
  __shared__ float sab[512];
  __shared__ float zz[544];
  __shared__ float redc[4];
  __shared__ float redd[4];

  const int b = blockIdx.x;
  const int t = threadIdx.x;
  const int i0 = t, i1 = t + 256;

  // load time-reversed absorb/atten
  float a0 = attenW[b * L_SZ + (L_SZ - 1 - i0)];
  float a1 = attenW[b * L_SZ + (L_SZ - 1 - i1)];
  sab[i0] = absorbW[b * L_SZ + (L_SZ - 1 - i0)];
  sab[i1] = absorbW[b * L_SZ + (L_SZ - 1 - i1)];
  s0[i0] = a0; s0[i1] = a1;
  __syncthreads();

  // Hillis-Steele inclusive scan (ping-pong)
  float* src = s0;
  float* dst = s1;
  for (int off = 1; off < 512; off <<= 1) {
    float v0 = src[i0] + ((i0 >= off) ? src[i0 - off] : 0.0f);
    float v1 = src[i1] + ((i1 >= off) ? src[i1 - off] : 0.0f);
    dst[i0] = v0; dst[i1] = v1;
    __syncthreads();
    float* tmp = src; src = dst; dst = tmp;
  }

  // captured partials: exp(-(incl - a)) * absorb_tb
  float p = expf(-(src[i0] - a0)) * sab[i0] + expf(-(src[i1] - a1)) * sab[i1];
#pragma unroll
  for (int off = 32; off; off >>= 1) p += __shfl_down(p, off, 64);
  if ((t & 63) == 0) redc[t >> 6] = p;

  // z = [Xg, pooled/L]
  if (t < G_SZ) zz[t] = Xg[b * G_SZ + t];
  zz[G_SZ + i0] = pooled[b * H2_SZ + i0] * (1.0f / (float)L_SZ);
  zz[G_SZ + i1] = pooled[b * H2_SZ + i1] * (1.0f / (float)L_SZ);
  __syncthreads();

  // d1[j] = gelu(z . Wd1[:,j] + bd1[j]);  v = d1[j] * Wd2[j]
  float s = bd1[t];
  for (int cc = 0; cc < G_SZ + H2_SZ; ++cc) s = fmaf(zz[cc], Wd1[cc * DH_SZ + t], s);
  float v = gelu_exact(s) * Wd2[t];
#pragma unroll
  for (int off = 32; off; off >>= 1) v += __shfl_down(v, off, 64);
  if ((t & 63) == 0) redd[t >> 6] = v;
  __syncthreads();

  if (t == 0) {
    float captured = redc[0] + redc[1] + redc[2] + redc[3];
    float d = redd[0] + redd[1] + redd[2] + redd[3] + bd2[0];
    out[b] = captured + d;
  }
}

// ---------------------------------------------------------------------------
extern "C" void kernel_launch(void* const* d_in, const int* in_sizes, int n_in,
                              void* d_out, int out_size, void* d_ws, size_t ws_size,
                              hipStream_t stream) {
  const float* Xg  = (const float*)d_in[0];
  const float* Xl  = (const float*)d_in[1];
  const float* W1  = (const float*)d_in[2];
  const float* b1  = (const float*)d_in[3];
  const float* W2  = (const float*)d_in[4];
  const float* b2  = (const float*)d_in[5];
  const float* wa  = (const float*)d_in[6];
  const float* ba  = (const float*)d_in[7];
  const float* wt  = (const float*)d_in[8];
  const float* bt  = (const float*)d_in[9];
  const float* Wd1 = (const float*)d_in[10];
  const float* bd1 = (const float*)d_in[11];
  const float* Wd2 = (const float*)d_in[12];
  const float* bd2 = (const float*)d_in[13];

  char* ws = (char*)d_ws;
  __bf16* W1p    = (__bf16*)(ws + 0);            //  65536 B
  __bf16* W2p    = (__bf16*)(ws + 65536);        // 524288 B
  float* absorbW = (float*)(ws + 589824);        // 524288 B
  float* attenW  = (float*)(ws + 1114112);       // 524288 B
  float* pooled  = (float*)(ws + 1638400);       // 524288 B  (end 2162688)

  repack_kernel<<<144, 256, 0, stream>>>(W1, W2, W1p, W2p, pooled);
  fused_kernel<<<M_SZ / ROWS, 1024, 0, stream>>>(Xl, W1p, W2p, b1, b2, wa, ba,
                                                 wt, bt, absorbW, attenW, pooled);
  finalize_kernel<<<B_SZ, 256, 0, stream>>>(Xg, absorbW, attenW, pooled,
                                            Wd1, bd1, Wd2, bd2, (float*)d_out);
}

// Round 14
// 142.630 us; speedup vs baseline: 1.1554x; 1.1554x over previous
//
#include <hip/hip_runtime.h>
#include <hip/hip_bf16.h>
#include <math.h>

// Shapes (fixed by the reference)
#define B_SZ   256
#define L_SZ   512
#define FD_SZ  64
#define H1_SZ  512
#define H2_SZ  512
#define G_SZ   32
#define DH_SZ  256
#define M_SZ   (B_SZ * L_SZ)   // 131072 rows

#define H1STRIDE 520           // padded row stride (elements): linear LDS addr

typedef __bf16 bfx8 __attribute__((ext_vector_type(8)));
typedef __bf16 bfx4 __attribute__((ext_vector_type(4)));
typedef float  f32x4 __attribute__((ext_vector_type(4)));
typedef float  f32x16 __attribute__((ext_vector_type(16)));

__device__ __forceinline__ float gelu_exact(float x) {
  return 0.5f * x * (1.0f + erff(x * 0.70710678118654752440f));
}
// tanh-form gelu via sigmoid; log2(e) folded in so v_exp_f32 is used directly.
__device__ __forceinline__ float gelu_fast(float x) {
  float x2 = x * x;
  float w = x * fmaf(0.102943398f, x2, 2.30220931f);
  float e = __builtin_amdgcn_exp2f(-w);
  return x * __builtin_amdgcn_rcpf(1.0f + e);
}
__device__ __forceinline__ float softplus_f(float x) {
  return (x > 20.0f) ? x : log1pf(expf(x));
}
__device__ __forceinline__ __bf16 f2bf(float f) { return (__bf16)f; }

// DPP row_ror:n within each 16-lane row (pure VALU, no LDS pipe).
#define ROR_ADD(x, n)                                                          \
  {                                                                            \
    int _t = __builtin_amdgcn_mov_dpp(__builtin_bit_cast(int, (x)),            \
                                      0x120 + (n), 0xF, 0xF, true);            \
    (x) += __builtin_bit_cast(float, _t);                                      \
  }

#define MFMA16(a, b, c) __builtin_amdgcn_mfma_f32_16x16x32_bf16((a), (b), (c), 0, 0, 0)
#define MFMA32(a, b, c) __builtin_amdgcn_mfma_f32_32x32x16_bf16((a), (b), (c), 0, 0, 0)

// ---------------------------------------------------------------------------
// Repack W1 (64x512) fp32 -> bf16 16x16x32-B-fragment order:
//   block id = mb*2 + ks; lane l holds W1[ks*32+(l>>4)*8+j][16*mb+(l&15)].
// Repack W2 (512x512) fp32 -> bf16 32x32x16-B-fragment order:
//   block id = nb*32 + ks; lane l holds W2[16*ks+(l>>5)*8+j][32*nb+(l&31)].
// Also zeroes `pooled` (512 KB).
// ---------------------------------------------------------------------------
__global__ void repack_kernel(const float* __restrict__ W1,
                              const float* __restrict__ W2,
                              __bf16* __restrict__ W1p,
                              __bf16* __restrict__ W2p,
                              float* __restrict__ pooled) {
  int t = blockIdx.x * 256 + threadIdx.x;
  if (t < 32768)
    *reinterpret_cast<float4*>(pooled + (size_t)t * 4) = (float4){0.f, 0.f, 0.f, 0.f};
  if (t < 4096) {  // W1: 64 blocks * 64 lanes
    int lane = t & 63, blk = t >> 6;
    int ks = blk & 1, mb = blk >> 1;
    int col = 16 * mb + (lane & 15);
    int kbase = ks * 32 + (lane >> 4) * 8;
    bfx8 o;
#pragma unroll
    for (int j = 0; j < 8; ++j) o[j] = f2bf(W1[(size_t)(kbase + j) * H1_SZ + col]);
    *reinterpret_cast<bfx8*>(W1p + (size_t)t * 8) = o;
  } else if (t < 4096 + 32768) {  // W2: 512 blocks * 64 lanes (32x32x16 frags)
    int t2 = t - 4096;
    int lane = t2 & 63, blk = t2 >> 6;
    int ks = blk & 31, nb = blk >> 5;
    int col = 32 * nb + (lane & 31);
    int kbase = 16 * ks + (lane >> 5) * 8;
    bfx8 o;
#pragma unroll
    for (int j = 0; j < 8; ++j) o[j] = f2bf(W2[(size_t)(kbase + j) * H2_SZ + col]);
    *reinterpret_cast<bfx8*>(W2p + (size_t)t2 * 8) = o;
  }
}

// ---------------------------------------------------------------------------
// Fused kernel: 64 rows per workgroup, 1024 threads (16 waves), 8 waves/SIMD.
//  GEMM1 (16x16x32, transposed): wave w -> h1 cols 32w..32w+31, rows 0..63.
//  GEMM2 (32x32x16): wave w = (rg = w>>3, cg = w&7) -> h2 cols 64cg..64cg+63
//    (nb = 2cg, 2cg+1), rows 32rg..32rg+31, K=512. One a2 ds_read feeds two
//    MFMAs; the per-q FMA collapses both col-blocks before the butterfly
//    tree (R7's lean-epilogue trick at R12's occupancy).
// H1s padded stride 520 (linear addressing). sl (4 KB) aliases dead Xs.
// LDS: 8K smem0 + 66.56K H1s ~= 74.6 KB -> 2 blocks/CU -> 32 waves/CU.
// ---------------------------------------------------------------------------
__global__ __launch_bounds__(1024, 8) void fused_kernel(
    const float* __restrict__ Xl,
    const __bf16* __restrict__ W1p, const __bf16* __restrict__ W2p,
    const float* __restrict__ b1, const float* __restrict__ b2,
    const float* __restrict__ wa, const float* __restrict__ ba,
    const float* __restrict__ wt, const float* __restrict__ bt,
    float* __restrict__ absorbW, float* __restrict__ attenW,
    float* __restrict__ pooled) {
  __shared__ __align__(16) char smem0[8192];  // Xs (GEMM1) then sl (epilogue)
  __shared__ __bf16 H1s[64 * H1STRIDE];       // 66.56 KB, padded, linear addr
  __bf16* Xs = reinterpret_cast<__bf16*>(smem0);  // 64x64, 16B-chunk XOR swz
  float*  sl = reinterpret_cast<float*>(smem0);   // 16 waves x 32 rows x 2

  const int tid = threadIdx.x;
  const int lane = tid & 63;
  const int w = tid >> 6;        // wave 0..15
  const int g = lane >> 4;       // k-group 0..3 (16x16x32 frags)
  const int c = lane & 15;       // row/col within 16x16 fragment
  const int c32 = lane & 31;     // col within 32x32 fragment
  const int kg = lane >> 5;      // k-group 0..1 (32x32x16 frags)
  const int rg = w >> 3;         // GEMM2 row-half 0..1
  const int cg = w & 7;          // GEMM2 col-pair 0..7
  const int R0 = blockIdx.x * 64;
  const int bidx = R0 >> 9;      // batch index (tiles aligned within batch)

  // ---- stage Xl tile (64x64 fp32 -> bf16 LDS, swizzled; convert ONCE) ----
  {
    int r = tid >> 4;             // 0..63
    int c4 = tid & 15;            // 16 float4 per row
    float4 v = *reinterpret_cast<const float4*>(Xl + (size_t)(R0 + r) * FD_SZ + c4 * 4);
    bfx4 bv;
    bv[0] = f2bf(v.x); bv[1] = f2bf(v.y); bv[2] = f2bf(v.z); bv[3] = f2bf(v.w);
    int chunk = c4 >> 1;          // 8-elem (16B) chunk 0..7
    int off = r * 64 + (((chunk ^ (r & 7)) << 3) + (c4 & 1) * 4);
    *reinterpret_cast<bfx4*>(&Xs[off]) = bv;
  }
  __syncthreads();

  // ---- GEMM1 (transposed): wave computes h1 cols 32w..32w+31, rows 0..63 --
  f32x4 acc1[2][4];
#pragma unroll
  for (int mi = 0; mi < 2; ++mi)
#pragma unroll
    for (int ni = 0; ni < 4; ++ni) acc1[mi][ni] = (f32x4){0.f, 0.f, 0.f, 0.f};

#pragma unroll
  for (int ks = 0; ks < 2; ++ks) {
    bfx8 a1[2];
#pragma unroll
    for (int mi = 0; mi < 2; ++mi) {
      int mb = 2 * w + mi;
      a1[mi] = *reinterpret_cast<const bfx8*>(W1p + ((size_t)(mb * 2 + ks) * 64 + lane) * 8);
    }
    bfx8 bx[4];
#pragma unroll
    for (int ni = 0; ni < 4; ++ni) {
      int r = 16 * ni + c;
      int chunk = ks * 4 + g;
      bx[ni] = *reinterpret_cast<const bfx8*>(&Xs[r * 64 + ((chunk ^ (r & 7)) << 3)]);
    }
#pragma unroll
    for (int mi = 0; mi < 2; ++mi)
#pragma unroll
      for (int ni = 0; ni < 4; ++ni)
        acc1[mi][ni] = MFMA16(a1[mi], bx[ni], acc1[mi][ni]);
  }

  // epilogue GEMM1: bias + gelu -> bf16 -> H1s[row][k], k = 16*mb + 4*g + reg
#pragma unroll
  for (int mi = 0; mi < 2; ++mi) {
    int mb = 2 * w + mi;
    float4 bias4 = *reinterpret_cast<const float4*>(b1 + 16 * mb + 4 * g);
#pragma unroll
    for (int ni = 0; ni < 4; ++ni) {
      int r = 16 * ni + c;                 // x-row (0..63)
      bfx4 pv;
      pv[0] = f2bf(gelu_fast(acc1[mi][ni][0] + bias4.x));
      pv[1] = f2bf(gelu_fast(acc1[mi][ni][1] + bias4.y));
      pv[2] = f2bf(gelu_fast(acc1[mi][ni][2] + bias4.z));
      pv[3] = f2bf(gelu_fast(acc1[mi][ni][3] + bias4.w));
      int off = r * H1STRIDE + 16 * mb + 4 * g;
      *reinterpret_cast<bfx4*>(&H1s[off]) = pv;
    }
  }
  __syncthreads();

  // ---- GEMM2 (32x32x16): wave (rg,cg): cols 64cg..64cg+63, rows 32rg.. ----
  f32x16 acc2[2];   // [ni] -> 32 AGPR
#pragma unroll
  for (int n = 0; n < 2; ++n)
#pragma unroll
    for (int q = 0; q < 16; ++q) acc2[n][q] = 0.0f;

  const __bf16* wpb = W2p + ((size_t)(2 * cg) * 32 * 64 + lane) * 8;
  const __bf16* h1base = &H1s[(32 * rg + c32) * H1STRIDE + 8 * kg];
  for (int ks = 0; ks < 32; ++ks) {
    bfx8 a2 = *reinterpret_cast<const bfx8*>(h1base + ks * 16);
    bfx8 bw0 = *reinterpret_cast<const bfx8*>(wpb + (size_t)ks * 512);
    bfx8 bw1 = *reinterpret_cast<const bfx8*>(wpb + (size_t)16384 + ks * 512);
    __builtin_amdgcn_s_setprio(1);
    acc2[0] = MFMA32(a2, bw0, acc2[0]);
    acc2[1] = MFMA32(a2, bw1, acc2[1]);
    __builtin_amdgcn_s_setprio(0);
  }

  // ---- epilogue GEMM2: bias+gelu, FMA-collapse cols, butterfly per row-pair
  // C layout (32x32): col = lane&31, row = (reg&3) + 8*(reg>>2) + 4*(lane>>5)
  const int col0 = 64 * cg + c32;
  const int col1 = col0 + 32;
  const float b2v0 = b2[col0], b2v1 = b2[col1];
  const float wav0 = wa[col0], wav1 = wa[col1];
  const float wtv0 = wt[col0], wtv1 = wt[col1];
  float pool0 = 0.0f, pool1 = 0.0f;
  const int rbase = 4 * kg;
  const bool hi16 = (lane & 16) != 0;

#pragma unroll
  for (int q = 0; q < 8; ++q) {
    int rA = 2 * q, rB = 2 * q + 1;
    float vA0 = gelu_fast(acc2[0][rA] + b2v0);
    float vA1 = gelu_fast(acc2[1][rA] + b2v1);
    float vB0 = gelu_fast(acc2[0][rB] + b2v0);
    float vB1 = gelu_fast(acc2[1][rB] + b2v1);
    pool0 += vA0 + vB0;
    pool1 += vA1 + vB1;
    float saA = fmaf(vA1, wav1, vA0 * wav0);
    float saB = fmaf(vB1, wav1, vB0 * wav0);
    float stA = fmaf(vA1, wtv1, vA0 * wtv0);
    float stB = fmaf(vB1, wtv1, vB0 * wtv0);
    // 2-for-1 butterfly at the xor16 level, then shared 16-lane DPP tree.
    float zs = hi16 ? saB : saA;
    float ys = hi16 ? saA : saB;
    float zt = hi16 ? stB : stA;
    float yt = hi16 ? stA : stB;
    ys = __shfl_xor(ys, 16, 64);
    yt = __shfl_xor(yt, 16, 64);
    float ss = zs + ys;         // lanes c32<16: rowA partial; >=16: rowB
    float tt = zt + yt;
    ROR_ADD(ss, 8); ROR_ADD(ss, 4); ROR_ADD(ss, 2); ROR_ADD(ss, 1);
    ROR_ADD(tt, 8); ROR_ADD(tt, 4); ROR_ADD(tt, 2); ROR_ADD(tt, 1);
    if (c32 == 0) {
      int row = (rA & 3) + 8 * (rA >> 2) + rbase;   // 0..31 within row-half
      *reinterpret_cast<float2*>(&sl[w * 64 + row * 2]) = make_float2(ss, tt);
    } else if (c32 == 16) {
      int row = (rB & 3) + 8 * (rB >> 2) + rbase;
      *reinterpret_cast<float2*>(&sl[w * 64 + row * 2]) = make_float2(ss, tt);
    }
  }
  // pooled: combine kg halves (rows), one atomic per col per wave
  pool0 += __shfl_xor(pool0, 32, 64);
  pool1 += __shfl_xor(pool1, 32, 64);
  if (lane < 32) {
    atomicAdd(&pooled[bidx * H2_SZ + col0], pool0);
    atomicAdd(&pooled[bidx * H2_SZ + col1], pool1);
  }
  __syncthreads();

  if (tid < 64) {
    int rgf = tid >> 5, rr = tid & 31;
    float sa = 0.0f, st = 0.0f;
#pragma unroll
    for (int cgf = 0; cgf < 8; ++cgf) {
      float2 v2 = *reinterpret_cast<float2*>(&sl[(rgf * 8 + cgf) * 64 + rr * 2]);
      sa += v2.x; st += v2.y;
    }
    absorbW[R0 + tid] = softplus_f(sa + ba[0]);
    attenW[R0 + tid]  = softplus_f(st + bt[0]);
  }
}

// ---------------------------------------------------------------------------
// Finalize: per-b reversed exclusive-cumsum scan + captured, pooled head, out
// ---------------------------------------------------------------------------
__global__ __launch_bounds__(256) void finalize_kernel(
    const float* __restrict__ Xg,
    const float* __restrict__ absorbW, const float* __restrict__ attenW,
    const float* __restrict__ pooled,
    const float* __restrict__ Wd1, const float* __restrict__ bd1,
    const float* __restrict__ Wd2, const float* __restrict__ bd2,
    float* __restrict__ out) {
  __shared__ float s0[512];
  __shared__ float s1[512];
  __shared__ float sab[512];
  __shared__ float zz[544];
  __shared__ float redc[4];
  __shared__ float redd[4];

  const int b = blockIdx.x;
  const int t = threadIdx.x;
  const int i0 = t, i1 = t + 256;

  // load time-reversed absorb/atten
  float a0 = attenW[b * L_SZ + (L_SZ - 1 - i0)];
  float a1 = attenW[b * L_SZ + (L_SZ - 1 - i1)];
  sab[i0] = absorbW[b * L_SZ + (L_SZ - 1 - i0)];
  sab[i1] = absorbW[b * L_SZ + (L_SZ - 1 - i1)];
  s0[i0] = a0; s0[i1] = a1;
  __syncthreads();

  // Hillis-Steele inclusive scan (ping-pong)
  float* src = s0;
  float* dst = s1;
  for (int off = 1; off < 512; off <<= 1) {
    float v0 = src[i0] + ((i0 >= off) ? src[i0 - off] : 0.0f);
    float v1 = src[i1] + ((i1 >= off) ? src[i1 - off] : 0.0f);
    dst[i0] = v0; dst[i1] = v1;
    __syncthreads();
    float* tmp = src; src = dst; dst = tmp;
  }

  // captured partials: exp(-(incl - a)) * absorb_tb
  float p = expf(-(src[i0] - a0)) * sab[i0] + expf(-(src[i1] - a1)) * sab[i1];
#pragma unroll
  for (int off = 32; off; off >>= 1) p += __shfl_down(p, off, 64);
  if ((t & 63) == 0) redc[t >> 6] = p;

  // z = [Xg, pooled/L]
  if (t < G_SZ) zz[t] = Xg[b * G_SZ + t];
  zz[G_SZ + i0] = pooled[b * H2_SZ + i0] * (1.0f / (float)L_SZ);
  zz[G_SZ + i1] = pooled[b * H2_SZ + i1] * (1.0f / (float)L_SZ);
  __syncthreads();

  // d1[j] = gelu(z . Wd1[:,j] + bd1[j]);  v = d1[j] * Wd2[j]
  float s = bd1[t];
  for (int cc = 0; cc < G_SZ + H2_SZ; ++cc) s = fmaf(zz[cc], Wd1[cc * DH_SZ + t], s);
  float v = gelu_exact(s) * Wd2[t];
#pragma unroll
  for (int off = 32; off; off >>= 1) v += __shfl_down(v, off, 64);
  if ((t & 63) == 0) redd[t >> 6] = v;
  __syncthreads();

  if (t == 0) {
    float captured = redc[0] + redc[1] + redc[2] + redc[3];
    float d = redd[0] + redd[1] + redd[2] + redd[3] + bd2[0];
    out[b] = captured + d;
  }
}

// ---------------------------------------------------------------------------
extern "C" void kernel_launch(void* const* d_in, const int* in_sizes, int n_in,
                              void* d_out, int out_size, void* d_ws, size_t ws_size,
                              hipStream_t stream) {
  const float* Xg  = (const float*)d_in[0];
  const float* Xl  = (const float*)d_in[1];
  const float* W1  = (const float*)d_in[2];
  const float* b1  = (const float*)d_in[3];
  const float* W2  = (const float*)d_in[4];
  const float* b2  = (const float*)d_in[5];
  const float* wa  = (const float*)d_in[6];
  const float* ba  = (const float*)d_in[7];
  const float* wt  = (const float*)d_in[8];
  const float* bt  = (const float*)d_in[9];
  const float* Wd1 = (const float*)d_in[10];
  const float* bd1 = (const float*)d_in[11];
  const float* Wd2 = (const float*)d_in[12];
  const float* bd2 = (const float*)d_in[13];

  char* ws = (char*)d_ws;
  __bf16* W1p    = (__bf16*)(ws + 0);            //  65536 B
  __bf16* W2p    = (__bf16*)(ws + 65536);        // 524288 B
  float* absorbW = (float*)(ws + 589824);        // 524288 B
  float* attenW  = (float*)(ws + 1114112);       // 524288 B
  float* pooled  = (float*)(ws + 1638400);       // 524288 B  (end 2162688)

  repack_kernel<<<144, 256, 0, stream>>>(W1, W2, W1p, W2p, pooled);
  fused_kernel<<<M_SZ / 64, 1024, 0, stream>>>(Xl, W1p, W2p, b1, b2, wa, ba,
                                               wt, bt, absorbW, attenW, pooled);
  finalize_kernel<<<B_SZ, 256, 0, stream>>>(Xg, absorbW, attenW, pooled,
                                            Wd1, bd1, Wd2, bd2, (float*)d_out);
}

// Round 15
// 137.788 us; speedup vs baseline: 1.1960x; 1.0351x over previous
//
#include <hip/hip_runtime.h>
#include <hip/hip_bf16.h>
#include <math.h>

// Shapes (fixed by the reference)
#define B_SZ   256
#define L_SZ   512
#define FD_SZ  64
#define H1_SZ  512
#define H2_SZ  512
#define G_SZ   32
#define DH_SZ  256
#define M_SZ   (B_SZ * L_SZ)   // 131072 rows

#define H1STRIDE 520           // padded row stride (elements): linear LDS addr

typedef __bf16 bfx8 __attribute__((ext_vector_type(8)));
typedef __bf16 bfx4 __attribute__((ext_vector_type(4)));
typedef float  f32x4 __attribute__((ext_vector_type(4)));
typedef float  f32x16 __attribute__((ext_vector_type(16)));

__device__ __forceinline__ float gelu_exact(float x) {
  return 0.5f * x * (1.0f + erff(x * 0.70710678118654752440f));
}
// tanh-form gelu via sigmoid; log2(e) folded in so v_exp_f32 is used directly.
__device__ __forceinline__ float gelu_fast(float x) {
  float x2 = x * x;
  float w = x * fmaf(0.102943398f, x2, 2.30220931f);
  float e = __builtin_amdgcn_exp2f(-w);
  return x * __builtin_amdgcn_rcpf(1.0f + e);
}
__device__ __forceinline__ float softplus_f(float x) {
  return (x > 20.0f) ? x : log1pf(expf(x));
}
__device__ __forceinline__ __bf16 f2bf(float f) { return (__bf16)f; }

// DPP row_ror:n within each 16-lane row (pure VALU, no LDS pipe).
#define ROR_ADD(x, n)                                                          \
  {                                                                            \
    int _t = __builtin_amdgcn_mov_dpp(__builtin_bit_cast(int, (x)),            \
                                      0x120 + (n), 0xF, 0xF, true);            \
    (x) += __builtin_bit_cast(float, _t);                                      \
  }

#define MFMA16(a, b, c) __builtin_amdgcn_mfma_f32_16x16x32_bf16((a), (b), (c), 0, 0, 0)
#define MFMA32(a, b, c) __builtin_amdgcn_mfma_f32_32x32x16_bf16((a), (b), (c), 0, 0, 0)

// ---------------------------------------------------------------------------
// Repack W1 (64x512) fp32 -> bf16 16x16x32-B-fragment order:
//   block id = mb*2 + ks; lane l holds W1[ks*32+(l>>4)*8+j][16*mb+(l&15)].
// Repack W2 (512x512) fp32 -> bf16 32x32x16-B-fragment order:
//   block id = nb*32 + ks; lane l holds W2[16*ks+(l>>5)*8+j][32*nb+(l&31)].
// Also zeroes `pooled` (512 KB).
// ---------------------------------------------------------------------------
__global__ void repack_kernel(const float* __restrict__ W1,
                              const float* __restrict__ W2,
                              __bf16* __restrict__ W1p,
                              __bf16* __restrict__ W2p,
                              float* __restrict__ pooled) {
  int t = blockIdx.x * 256 + threadIdx.x;
  if (t < 32768)
    *reinterpret_cast<float4*>(pooled + (size_t)t * 4) = (float4){0.f, 0.f, 0.f, 0.f};
  if (t < 4096) {  // W1: 64 blocks * 64 lanes
    int lane = t & 63, blk = t >> 6;
    int ks = blk & 1, mb = blk >> 1;
    int col = 16 * mb + (lane & 15);
    int kbase = ks * 32 + (lane >> 4) * 8;
    bfx8 o;
#pragma unroll
    for (int j = 0; j < 8; ++j) o[j] = f2bf(W1[(size_t)(kbase + j) * H1_SZ + col]);
    *reinterpret_cast<bfx8*>(W1p + (size_t)t * 8) = o;
  } else if (t < 4096 + 32768) {  // W2: 512 blocks * 64 lanes (32x32x16 frags)
    int t2 = t - 4096;
    int lane = t2 & 63, blk = t2 >> 6;
    int ks = blk & 31, nb = blk >> 5;
    int col = 32 * nb + (lane & 31);
    int kbase = 16 * ks + (lane >> 5) * 8;
    bfx8 o;
#pragma unroll
    for (int j = 0; j < 8; ++j) o[j] = f2bf(W2[(size_t)(kbase + j) * H2_SZ + col]);
    *reinterpret_cast<bfx8*>(W2p + (size_t)t2 * 8) = o;
  }
}

// ---------------------------------------------------------------------------
// Fused kernel: 64 rows per workgroup, 1024 threads (16 waves), 8 waves/SIMD.
// Wave w owns 32 h-columns.
//  GEMM1 (16x16x32, transposed): h1 cols 32w..32w+31, all 64 rows.
//  GEMM2 (32x32x16): h2 cols 32w..32w+31 (nb=w), rows 0..63, K=512,
//    with a 1-deep rolled W2 prefetch (bw loaded one ks ahead; fits in the
//    existing 32V allocation -> no occupancy cost).
//  Epilogue: butterfly-reduced absorb/atten + pooled.
// H1s uses PADDED stride 520 (no XOR): all LDS addresses are base+immediate.
// LDS: 65 KB H1s + 8 KB (Xs aliased with sl) = 73 KB -> 2 blocks/CU.
// ---------------------------------------------------------------------------
__global__ __launch_bounds__(1024, 8) void fused_kernel(
    const float* __restrict__ Xl,
    const __bf16* __restrict__ W1p, const __bf16* __restrict__ W2p,
    const float* __restrict__ b1, const float* __restrict__ b2,
    const float* __restrict__ wa, const float* __restrict__ ba,
    const float* __restrict__ wt, const float* __restrict__ bt,
    float* __restrict__ absorbW, float* __restrict__ attenW,
    float* __restrict__ pooled) {
  __shared__ __align__(16) char smem0[8192];  // Xs (GEMM1) then sl (epilogue)
  __shared__ __bf16 H1s[64 * H1STRIDE];       // 65 KB, padded, linear addr
  __bf16* Xs = reinterpret_cast<__bf16*>(smem0);  // 64x64, 16B-chunk XOR swz
  float*  sl = reinterpret_cast<float*>(smem0);   // 16 waves x 64 rows x 2

  const int tid = threadIdx.x;
  const int lane = tid & 63;
  const int w = tid >> 6;        // wave 0..15
  const int g = lane >> 4;       // k-group 0..3 (16x16x32 frags)
  const int c = lane & 15;       // row/col within 16x16 fragment
  const int c32 = lane & 31;     // col within 32x32 fragment
  const int kg = lane >> 5;      // k-group 0..1 (32x32x16 frags)
  const int R0 = blockIdx.x * 64;
  const int bidx = R0 >> 9;      // batch index (tiles aligned within batch)

  // ---- stage Xl tile (64x64 fp32 -> bf16 LDS, swizzled; convert ONCE) ----
  {
    int r = tid >> 4;             // 0..63
    int c4 = tid & 15;            // 16 float4 per row
    float4 v = *reinterpret_cast<const float4*>(Xl + (size_t)(R0 + r) * FD_SZ + c4 * 4);
    bfx4 bv;
    bv[0] = f2bf(v.x); bv[1] = f2bf(v.y); bv[2] = f2bf(v.z); bv[3] = f2bf(v.w);
    int chunk = c4 >> 1;          // 8-elem (16B) chunk 0..7
    int off = r * 64 + (((chunk ^ (r & 7)) << 3) + (c4 & 1) * 4);
    *reinterpret_cast<bfx4*>(&Xs[off]) = bv;
  }
  __syncthreads();

  // ---- GEMM1 (transposed): wave computes h1 cols 32w..32w+31 --------------
  f32x4 acc1[2][4];
#pragma unroll
  for (int mi = 0; mi < 2; ++mi)
#pragma unroll
    for (int ni = 0; ni < 4; ++ni) acc1[mi][ni] = (f32x4){0.f, 0.f, 0.f, 0.f};

#pragma unroll
  for (int ks = 0; ks < 2; ++ks) {
    bfx8 a1[2];
#pragma unroll
    for (int mi = 0; mi < 2; ++mi) {
      int mb = 2 * w + mi;
      a1[mi] = *reinterpret_cast<const bfx8*>(W1p + ((size_t)(mb * 2 + ks) * 64 + lane) * 8);
    }
    bfx8 bx[4];
#pragma unroll
    for (int ni = 0; ni < 4; ++ni) {
      int r = 16 * ni + c;
      int chunk = ks * 4 + g;
      bx[ni] = *reinterpret_cast<const bfx8*>(&Xs[r * 64 + ((chunk ^ (r & 7)) << 3)]);
    }
#pragma unroll
    for (int mi = 0; mi < 2; ++mi)
#pragma unroll
      for (int ni = 0; ni < 4; ++ni)
        acc1[mi][ni] = MFMA16(a1[mi], bx[ni], acc1[mi][ni]);
  }

  // epilogue GEMM1: bias + gelu -> bf16 -> H1s[row][k], k = 16*mb + 4*g + reg
#pragma unroll
  for (int mi = 0; mi < 2; ++mi) {
    int mb = 2 * w + mi;
    float4 bias4 = *reinterpret_cast<const float4*>(b1 + 16 * mb + 4 * g);
#pragma unroll
    for (int ni = 0; ni < 4; ++ni) {
      int r = 16 * ni + c;                 // x-row (0..63)
      bfx4 pv;
      pv[0] = f2bf(gelu_fast(acc1[mi][ni][0] + bias4.x));
      pv[1] = f2bf(gelu_fast(acc1[mi][ni][1] + bias4.y));
      pv[2] = f2bf(gelu_fast(acc1[mi][ni][2] + bias4.z));
      pv[3] = f2bf(gelu_fast(acc1[mi][ni][3] + bias4.w));
      int off = r * H1STRIDE + 16 * mb + 4 * g;
      *reinterpret_cast<bfx4*>(&H1s[off]) = pv;
    }
  }
  __syncthreads();

  // ---- GEMM2 (32x32x16): wave w owns cols 32w..32w+31 (nb=w), rows 0..63 --
  // 1-deep W2 prefetch: bwn issued before the ds_reads, consumed next iter.
  f32x16 acc2[2];   // [mblk] -> 32 AGPR
#pragma unroll
  for (int m = 0; m < 2; ++m)
#pragma unroll
    for (int q = 0; q < 16; ++q) acc2[m][q] = 0.0f;

  const __bf16* wpb = W2p + ((size_t)w * 32 * 64 + lane) * 8;
  const __bf16* h1base = &H1s[c32 * H1STRIDE + 8 * kg];
  bfx8 bw = *reinterpret_cast<const bfx8*>(wpb);
#pragma unroll 1
  for (int ks = 0; ks < 31; ++ks) {
    bfx8 bwn = *reinterpret_cast<const bfx8*>(wpb + (size_t)(ks + 1) * 512);
    bfx8 a2[2];
#pragma unroll
    for (int m = 0; m < 2; ++m)   // offset = m*32*520 + ks*16 elems
      a2[m] = *reinterpret_cast<const bfx8*>(h1base + m * 32 * H1STRIDE + ks * 16);
    __builtin_amdgcn_s_setprio(1);
    acc2[0] = MFMA32(a2[0], bw, acc2[0]);
    acc2[1] = MFMA32(a2[1], bw, acc2[1]);
    __builtin_amdgcn_s_setprio(0);
    bw = bwn;
  }
  {  // peeled last iteration (ks = 31)
    bfx8 a2[2];
#pragma unroll
    for (int m = 0; m < 2; ++m)
      a2[m] = *reinterpret_cast<const bfx8*>(h1base + m * 32 * H1STRIDE + 31 * 16);
    acc2[0] = MFMA32(a2[0], bw, acc2[0]);
    acc2[1] = MFMA32(a2[1], bw, acc2[1]);
  }

  // ---- epilogue GEMM2: bias+gelu, butterfly-reduce absorb/atten + pooled ---
  // C layout (32x32): col = lane&31, row = (reg&3) + 8*(reg>>2) + 4*(lane>>5)
  const int col = 32 * w + c32;
  const float b2v = b2[col];
  const float wav = wa[col];
  const float wtv = wt[col];
  float pool0 = 0.0f;
  const int rbase = 4 * kg;
  const bool hi16 = (lane & 16) != 0;

#pragma unroll
  for (int m = 0; m < 2; ++m) {
#pragma unroll
    for (int q = 0; q < 8; ++q) {
      int rA = 2 * q, rB = 2 * q + 1;
      float vA = gelu_fast(acc2[m][rA] + b2v);
      float vB = gelu_fast(acc2[m][rB] + b2v);
      pool0 += vA + vB;
      float saA = vA * wav, saB = vB * wav;
      float stA = vA * wtv, stB = vB * wtv;
      // 2-for-1 butterfly at the xor16 level, then shared 16-lane DPP tree.
      float zs = hi16 ? saB : saA;
      float ys = hi16 ? saA : saB;
      float zt = hi16 ? stB : stA;
      float yt = hi16 ? stA : stB;
      ys = __shfl_xor(ys, 16, 64);
      yt = __shfl_xor(yt, 16, 64);
      float ss = zs + ys;         // lanes c32<16: rowA partial; >=16: rowB
      float tt = zt + yt;
      ROR_ADD(ss, 8); ROR_ADD(ss, 4); ROR_ADD(ss, 2); ROR_ADD(ss, 1);
      ROR_ADD(tt, 8); ROR_ADD(tt, 4); ROR_ADD(tt, 2); ROR_ADD(tt, 1);
      if (c32 == 0) {
        int row = 32 * m + (rA & 3) + 8 * (rA >> 2) + rbase;
        *reinterpret_cast<float2*>(&sl[w * 128 + row * 2]) = make_float2(ss, tt);
      } else if (c32 == 16) {
        int row = 32 * m + (rB & 3) + 8 * (rB >> 2) + rbase;
        *reinterpret_cast<float2*>(&sl[w * 128 + row * 2]) = make_float2(ss, tt);
      }
    }
  }
  // pooled: col sums need the two lane-halves (row sets) combined
  pool0 += __shfl_xor(pool0, 32, 64);
  if (lane < 32)
    atomicAdd(&pooled[bidx * H2_SZ + col], pool0);
  __syncthreads();

  if (tid < 64) {
    float sa = 0.0f, st = 0.0f;
#pragma unroll
    for (int w16 = 0; w16 < 16; ++w16) {
      float2 v2 = *reinterpret_cast<float2*>(&sl[w16 * 128 + tid * 2]);
      sa += v2.x; st += v2.y;
    }
    absorbW[R0 + tid] = softplus_f(sa + ba[0]);
    attenW[R0 + tid]  = softplus_f(st + bt[0]);
  }
}

// ---------------------------------------------------------------------------
// Finalize (512 threads): reversed exclusive-cumsum scan + captured, head, out
// Head dot split-K across two 256-thread halves.
// ---------------------------------------------------------------------------
__global__ __launch_bounds__(512) void finalize_kernel(
    const float* __restrict__ Xg,
    const float* __restrict__ absorbW, const float* __restrict__ attenW,
    const float* __restrict__ pooled,
    const float* __restrict__ Wd1, const float* __restrict__ bd1,
    const float* __restrict__ Wd2, const float* __restrict__ bd2,
    float* __restrict__ out) {
  __shared__ float s0[512];
  __shared__ float s1[512];
  __shared__ float zz[544];
  __shared__ float part[512];
  __shared__ float redc[8];
  __shared__ float redd[4];

  const int b = blockIdx.x;
  const int t = threadIdx.x;

  // load time-reversed absorb/atten (1 elem/thread); stage z = [Xg, pooled/L]
  float av   = attenW[b * L_SZ + (L_SZ - 1 - t)];
  float sabv = absorbW[b * L_SZ + (L_SZ - 1 - t)];
  s0[t] = av;
  zz[G_SZ + t] = pooled[b * H2_SZ + t] * (1.0f / (float)L_SZ);
  if (t < G_SZ) zz[t] = Xg[b * G_SZ + t];
  __syncthreads();

  // Hillis-Steele inclusive scan over 512 (ping-pong, 1 elem/thread)
  float* src = s0;
  float* dst = s1;
  for (int off = 1; off < 512; off <<= 1) {
    dst[t] = src[t] + ((t >= off) ? src[t - off] : 0.0f);
    __syncthreads();
    float* tmp = src; src = dst; dst = tmp;
  }

  // captured partials: exp(-(incl - a)) * absorb_tb
  float p = __expf(-(src[t] - av)) * sabv;
#pragma unroll
  for (int off = 32; off; off >>= 1) p += __shfl_down(p, off, 64);
  if ((t & 63) == 0) redc[t >> 6] = p;

  // head split-K: thread (j = t&255, half = t>>8) does 272 of the 544 terms
  {
    int j = t & 255, half = t >> 8;
    float s = half ? 0.0f : bd1[j];
    int cc0 = half * 272;
    for (int cc = cc0; cc < cc0 + 272; ++cc)
      s = fmaf(zz[cc], Wd1[(size_t)cc * DH_SZ + j], s);
    part[t] = s;
  }
  __syncthreads();

  float dv = 0.0f;
  if (t < DH_SZ) {
    float d1 = part[t] + part[t + 256];
    dv = gelu_exact(d1) * Wd2[t];
  }
#pragma unroll
  for (int off = 32; off; off >>= 1) dv += __shfl_down(dv, off, 64);
  if (t < DH_SZ && (t & 63) == 0) redd[t >> 6] = dv;
  __syncthreads();

  if (t == 0) {
    float captured = 0.0f;
#pragma unroll
    for (int i = 0; i < 8; ++i) captured += redc[i];
    float d = redd[0] + redd[1] + redd[2] + redd[3] + bd2[0];
    out[b] = captured + d;
  }
}

// ---------------------------------------------------------------------------
extern "C" void kernel_launch(void* const* d_in, const int* in_sizes, int n_in,
                              void* d_out, int out_size, void* d_ws, size_t ws_size,
                              hipStream_t stream) {
  const float* Xg  = (const float*)d_in[0];
  const float* Xl  = (const float*)d_in[1];
  const float* W1  = (const float*)d_in[2];
  const float* b1  = (const float*)d_in[3];
  const float* W2  = (const float*)d_in[4];
  const float* b2  = (const float*)d_in[5];
  const float* wa  = (const float*)d_in[6];
  const float* ba  = (const float*)d_in[7];
  const float* wt  = (const float*)d_in[8];
  const float* bt  = (const float*)d_in[9];
  const float* Wd1 = (const float*)d_in[10];
  const float* bd1 = (const float*)d_in[11];
  const float* Wd2 = (const float*)d_in[12];
  const float* bd2 = (const float*)d_in[13];

  char* ws = (char*)d_ws;
  __bf16* W1p    = (__bf16*)(ws + 0);            //  65536 B
  __bf16* W2p    = (__bf16*)(ws + 65536);        // 524288 B
  float* absorbW = (float*)(ws + 589824);        // 524288 B
  float* attenW  = (float*)(ws + 1114112);       // 524288 B
  float* pooled  = (float*)(ws + 1638400);       // 524288 B  (end 2162688)

  repack_kernel<<<144, 256, 0, stream>>>(W1, W2, W1p, W2p, pooled);
  fused_kernel<<<M_SZ / 64, 1024, 0, stream>>>(Xl, W1p, W2p, b1, b2, wa, ba,
                                               wt, bt, absorbW, attenW, pooled);
  finalize_kernel<<<B_SZ, 512, 0, stream>>>(Xg, absorbW, attenW, pooled,
                                            Wd1, bd1, Wd2, bd2, (float*)d_out);
}

// Round 16
// 134.077 us; speedup vs baseline: 1.2291x; 1.0277x over previous
//
#include <hip/hip_runtime.h>
#include <hip/hip_bf16.h>
#include <math.h>

// Shapes (fixed by the reference)
#define B_SZ   256
#define L_SZ   512
#define FD_SZ  64
#define H1_SZ  512
#define H2_SZ  512
#define G_SZ   32
#define DH_SZ  256
#define M_SZ   (B_SZ * L_SZ)   // 131072 rows

#define H1STRIDE 520           // padded row stride (elements): linear LDS addr

typedef __bf16 bfx8 __attribute__((ext_vector_type(8)));
typedef __bf16 bfx4 __attribute__((ext_vector_type(4)));
typedef float  f32x4 __attribute__((ext_vector_type(4)));
typedef float  f32x16 __attribute__((ext_vector_type(16)));

__device__ __forceinline__ float gelu_exact(float x) {
  return 0.5f * x * (1.0f + erff(x * 0.70710678118654752440f));
}
// tanh-form gelu via sigmoid; log2(e) folded in so v_exp_f32 is used directly.
__device__ __forceinline__ float gelu_fast(float x) {
  float x2 = x * x;
  float w = x * fmaf(0.102943398f, x2, 2.30220931f);
  float e = __builtin_amdgcn_exp2f(-w);
  return x * __builtin_amdgcn_rcpf(1.0f + e);
}
__device__ __forceinline__ float softplus_f(float x) {
  return (x > 20.0f) ? x : log1pf(expf(x));
}
__device__ __forceinline__ __bf16 f2bf(float f) { return (__bf16)f; }

// DPP row_ror:n within each 16-lane row (pure VALU, no LDS pipe).
#define ROR_ADD(x, n)                                                          \
  {                                                                            \
    int _t = __builtin_amdgcn_mov_dpp(__builtin_bit_cast(int, (x)),            \
                                      0x120 + (n), 0xF, 0xF, true);            \
    (x) += __builtin_bit_cast(float, _t);                                      \
  }

#define MFMA16(a, b, c) __builtin_amdgcn_mfma_f32_16x16x32_bf16((a), (b), (c), 0, 0, 0)
#define MFMA32(a, b, c) __builtin_amdgcn_mfma_f32_32x32x16_bf16((a), (b), (c), 0, 0, 0)

// ---------------------------------------------------------------------------
// Repack W1 (64x512) fp32 -> bf16 16x16x32-B-fragment order:
//   block id = mb*2 + ks; lane l holds W1[ks*32+(l>>4)*8+j][16*mb+(l&15)].
// Repack W2 (512x512) fp32 -> bf16 32x32x16-B-fragment order:
//   block id = nb*32 + ks; lane l holds W2[16*ks+(l>>5)*8+j][32*nb+(l&31)].
// Also zeroes `pooled` (512 KB).
// ---------------------------------------------------------------------------
__global__ void repack_kernel(const float* __restrict__ W1,
                              const float* __restrict__ W2,
                              __bf16* __restrict__ W1p,
                              __bf16* __restrict__ W2p,
                              float* __restrict__ pooled) {
  int t = blockIdx.x * 256 + threadIdx.x;
  if (t < 32768)
    *reinterpret_cast<float4*>(pooled + (size_t)t * 4) = (float4){0.f, 0.f, 0.f, 0.f};
  if (t < 4096) {  // W1: 64 blocks * 64 lanes
    int lane = t & 63, blk = t >> 6;
    int ks = blk & 1, mb = blk >> 1;
    int col = 16 * mb + (lane & 15);
    int kbase = ks * 32 + (lane >> 4) * 8;
    bfx8 o;
#pragma unroll
    for (int j = 0; j < 8; ++j) o[j] = f2bf(W1[(size_t)(kbase + j) * H1_SZ + col]);
    *reinterpret_cast<bfx8*>(W1p + (size_t)t * 8) = o;
  } else if (t < 4096 + 32768) {  // W2: 512 blocks * 64 lanes (32x32x16 frags)
    int t2 = t - 4096;
    int lane = t2 & 63, blk = t2 >> 6;
    int ks = blk & 31, nb = blk >> 5;
    int col = 32 * nb + (lane & 31);
    int kbase = 16 * ks + (lane >> 5) * 8;
    bfx8 o;
#pragma unroll
    for (int j = 0; j < 8; ++j) o[j] = f2bf(W2[(size_t)(kbase + j) * H2_SZ + col]);
    *reinterpret_cast<bfx8*>(W2p + (size_t)t2 * 8) = o;
  }
}

// ---------------------------------------------------------------------------
// Fused kernel (R12 form): 64 rows per workgroup, 1024 threads (16 waves),
// 8 waves/SIMD. Wave w owns 32 h-columns.
//  GEMM1 (16x16x32, transposed): h1 cols 32w..32w+31, all 64 rows.
//  GEMM2 (32x32x16): h2 cols 32w..32w+31 (nb=w), rows 0..63, K=512.
//  Epilogue: butterfly-reduced absorb/atten + pooled.
// H1s uses PADDED stride 520 (no XOR): all LDS addresses are base+immediate.
// LDS: 65 KB H1s + 8 KB (Xs aliased with sl) = 73 KB -> 2 blocks/CU.
// ---------------------------------------------------------------------------
__global__ __launch_bounds__(1024, 8) void fused_kernel(
    const float* __restrict__ Xl,
    const __bf16* __restrict__ W1p, const __bf16* __restrict__ W2p,
    const float* __restrict__ b1, const float* __restrict__ b2,
    const float* __restrict__ wa, const float* __restrict__ ba,
    const float* __restrict__ wt, const float* __restrict__ bt,
    float* __restrict__ absorbW, float* __restrict__ attenW,
    float* __restrict__ pooled) {
  __shared__ __align__(16) char smem0[8192];  // Xs (GEMM1) then sl (epilogue)
  __shared__ __bf16 H1s[64 * H1STRIDE];       // 65 KB, padded, linear addr
  __bf16* Xs = reinterpret_cast<__bf16*>(smem0);  // 64x64, 16B-chunk XOR swz
  float*  sl = reinterpret_cast<float*>(smem0);   // 16 waves x 64 rows x 2

  const int tid = threadIdx.x;
  const int lane = tid & 63;
  const int w = tid >> 6;        // wave 0..15
  const int g = lane >> 4;       // k-group 0..3 (16x16x32 frags)
  const int c = lane & 15;       // row/col within 16x16 fragment
  const int c32 = lane & 31;     // col within 32x32 fragment
  const int kg = lane >> 5;      // k-group 0..1 (32x32x16 frags)
  const int R0 = blockIdx.x * 64;
  const int bidx = R0 >> 9;      // batch index (tiles aligned within batch)

  // ---- stage Xl tile (64x64 fp32 -> bf16 LDS, swizzled; convert ONCE) ----
  {
    int r = tid >> 4;             // 0..63
    int c4 = tid & 15;            // 16 float4 per row
    float4 v = *reinterpret_cast<const float4*>(Xl + (size_t)(R0 + r) * FD_SZ + c4 * 4);
    bfx4 bv;
    bv[0] = f2bf(v.x); bv[1] = f2bf(v.y); bv[2] = f2bf(v.z); bv[3] = f2bf(v.w);
    int chunk = c4 >> 1;          // 8-elem (16B) chunk 0..7
    int off = r * 64 + (((chunk ^ (r & 7)) << 3) + (c4 & 1) * 4);
    *reinterpret_cast<bfx4*>(&Xs[off]) = bv;
  }
  __syncthreads();

  // ---- GEMM1 (transposed): wave computes h1 cols 32w..32w+31 --------------
  f32x4 acc1[2][4];
#pragma unroll
  for (int mi = 0; mi < 2; ++mi)
#pragma unroll
    for (int ni = 0; ni < 4; ++ni) acc1[mi][ni] = (f32x4){0.f, 0.f, 0.f, 0.f};

#pragma unroll
  for (int ks = 0; ks < 2; ++ks) {
    bfx8 a1[2];
#pragma unroll
    for (int mi = 0; mi < 2; ++mi) {
      int mb = 2 * w + mi;
      a1[mi] = *reinterpret_cast<const bfx8*>(W1p + ((size_t)(mb * 2 + ks) * 64 + lane) * 8);
    }
    bfx8 bx[4];
#pragma unroll
    for (int ni = 0; ni < 4; ++ni) {
      int r = 16 * ni + c;
      int chunk = ks * 4 + g;
      bx[ni] = *reinterpret_cast<const bfx8*>(&Xs[r * 64 + ((chunk ^ (r & 7)) << 3)]);
    }
#pragma unroll
    for (int mi = 0; mi < 2; ++mi)
#pragma unroll
      for (int ni = 0; ni < 4; ++ni)
        acc1[mi][ni] = MFMA16(a1[mi], bx[ni], acc1[mi][ni]);
  }

  // epilogue GEMM1: bias + gelu -> bf16 -> H1s[row][k], k = 16*mb + 4*g + reg
#pragma unroll
  for (int mi = 0; mi < 2; ++mi) {
    int mb = 2 * w + mi;
    float4 bias4 = *reinterpret_cast<const float4*>(b1 + 16 * mb + 4 * g);
#pragma unroll
    for (int ni = 0; ni < 4; ++ni) {
      int r = 16 * ni + c;                 // x-row (0..63)
      bfx4 pv;
      pv[0] = f2bf(gelu_fast(acc1[mi][ni][0] + bias4.x));
      pv[1] = f2bf(gelu_fast(acc1[mi][ni][1] + bias4.y));
      pv[2] = f2bf(gelu_fast(acc1[mi][ni][2] + bias4.z));
      pv[3] = f2bf(gelu_fast(acc1[mi][ni][3] + bias4.w));
      int off = r * H1STRIDE + 16 * mb + 4 * g;
      *reinterpret_cast<bfx4*>(&H1s[off]) = pv;
    }
  }
  __syncthreads();

  // ---- GEMM2 (32x32x16): wave w owns cols 32w..32w+31 (nb=w), rows 0..63 --
  f32x16 acc2[2];   // [mblk] -> 32 AGPR
#pragma unroll
  for (int m = 0; m < 2; ++m)
#pragma unroll
    for (int q = 0; q < 16; ++q) acc2[m][q] = 0.0f;

  const __bf16* wpb = W2p + ((size_t)w * 32 * 64 + lane) * 8;
  const __bf16* h1base = &H1s[c32 * H1STRIDE + 8 * kg];
  for (int ks = 0; ks < 32; ++ks) {
    bfx8 a2[2];
#pragma unroll
    for (int m = 0; m < 2; ++m)   // offset = m*32*520 + ks*16 elems (imm)
      a2[m] = *reinterpret_cast<const bfx8*>(h1base + m * 32 * H1STRIDE + ks * 16);
    bfx8 bw = *reinterpret_cast<const bfx8*>(wpb + (size_t)ks * 512);
    __builtin_amdgcn_s_setprio(1);
    acc2[0] = MFMA32(a2[0], bw, acc2[0]);
    acc2[1] = MFMA32(a2[1], bw, acc2[1]);
    __builtin_amdgcn_s_setprio(0);
  }

  // ---- epilogue GEMM2: bias+gelu, butterfly-reduce absorb/atten + pooled ---
  // C layout (32x32): col = lane&31, row = (reg&3) + 8*(reg>>2) + 4*(lane>>5)
  const int col = 32 * w + c32;
  const float b2v = b2[col];
  const float wav = wa[col];
  const float wtv = wt[col];
  float pool0 = 0.0f;
  const int rbase = 4 * kg;
  const bool hi16 = (lane & 16) != 0;

#pragma unroll
  for (int m = 0; m < 2; ++m) {
#pragma unroll
    for (int q = 0; q < 8; ++q) {
      int rA = 2 * q, rB = 2 * q + 1;
      float vA = gelu_fast(acc2[m][rA] + b2v);
      float vB = gelu_fast(acc2[m][rB] + b2v);
      pool0 += vA + vB;
      float saA = vA * wav, saB = vB * wav;
      float stA = vA * wtv, stB = vB * wtv;
      // 2-for-1 butterfly at the xor16 level, then shared 16-lane DPP tree.
      float zs = hi16 ? saB : saA;
      float ys = hi16 ? saA : saB;
      float zt = hi16 ? stB : stA;
      float yt = hi16 ? stA : stB;
      ys = __shfl_xor(ys, 16, 64);
      yt = __shfl_xor(yt, 16, 64);
      float ss = zs + ys;         // lanes c32<16: rowA partial; >=16: rowB
      float tt = zt + yt;
      ROR_ADD(ss, 8); ROR_ADD(ss, 4); ROR_ADD(ss, 2); ROR_ADD(ss, 1);
      ROR_ADD(tt, 8); ROR_ADD(tt, 4); ROR_ADD(tt, 2); ROR_ADD(tt, 1);
      if (c32 == 0) {
        int row = 32 * m + (rA & 3) + 8 * (rA >> 2) + rbase;
        *reinterpret_cast<float2*>(&sl[w * 128 + row * 2]) = make_float2(ss, tt);
      } else if (c32 == 16) {
        int row = 32 * m + (rB & 3) + 8 * (rB >> 2) + rbase;
        *reinterpret_cast<float2*>(&sl[w * 128 + row * 2]) = make_float2(ss, tt);
      }
    }
  }
  // pooled: col sums need the two lane-halves (row sets) combined
  pool0 += __shfl_xor(pool0, 32, 64);
  if (lane < 32)
    atomicAdd(&pooled[bidx * H2_SZ + col], pool0);
  __syncthreads();

  if (tid < 64) {
    float sa = 0.0f, st = 0.0f;
#pragma unroll
    for (int w16 = 0; w16 < 16; ++w16) {
      float2 v2 = *reinterpret_cast<float2*>(&sl[w16 * 128 + tid * 2]);
      sa += v2.x; st += v2.y;
    }
    absorbW[R0 + tid] = softplus_f(sa + ba[0]);
    attenW[R0 + tid]  = softplus_f(st + bt[0]);
  }
}

// ---------------------------------------------------------------------------
// Finalize (512 threads): reversed exclusive-cumsum scan + captured, head, out
// Head dot split-K across two 256-thread halves.
// ---------------------------------------------------------------------------
__global__ __launch_bounds__(512) void finalize_kernel(
    const float* __restrict__ Xg,
    const float* __restrict__ absorbW, const float* __restrict__ attenW,
    const float* __restrict__ pooled,
    const float* __restrict__ Wd1, const float* __restrict__ bd1,
    const float* __restrict__ Wd2, const float* __restrict__ bd2,
    float* __restrict__ out) {
  __shared__ float s0[512];
  __shared__ float s1[512];
  __shared__ float zz[544];
  __shared__ float part[512];
  __shared__ float redc[8];
  __shared__ float redd[4];

  const int b = blockIdx.x;
  const int t = threadIdx.x;

  // load time-reversed absorb/atten (1 elem/thread); stage z = [Xg, pooled/L]
  float av   = attenW[b * L_SZ + (L_SZ - 1 - t)];
  float sabv = absorbW[b * L_SZ + (L_SZ - 1 - t)];
  s0[t] = av;
  zz[G_SZ + t] = pooled[b * H2_SZ + t] * (1.0f / (float)L_SZ);
  if (t < G_SZ) zz[t] = Xg[b * G_SZ + t];
  __syncthreads();

  // Hillis-Steele inclusive scan over 512 (ping-pong, 1 elem/thread)
  float* src = s0;
  float* dst = s1;
  for (int off = 1; off < 512; off <<= 1) {
    dst[t] = src[t] + ((t >= off) ? src[t - off] : 0.0f);
    __syncthreads();
    float* tmp = src; src = dst; dst = tmp;
  }

  // captured partials: exp(-(incl - a)) * absorb_tb
  float p = __expf(-(src[t] - av)) * sabv;
#pragma unroll
  for (int off = 32; off; off >>= 1) p += __shfl_down(p, off, 64);
  if ((t & 63) == 0) redc[t >> 6] = p;

  // head split-K: thread (j = t&255, half = t>>8) does 272 of the 544 terms
  {
    int j = t & 255, half = t >> 8;
    float s = half ? 0.0f : bd1[j];
    int cc0 = half * 272;
    for (int cc = cc0; cc < cc0 + 272; ++cc)
      s = fmaf(zz[cc], Wd1[(size_t)cc * DH_SZ + j], s);
    part[t] = s;
  }
  __syncthreads();

  float dv = 0.0f;
  if (t < DH_SZ) {
    float d1 = part[t] + part[t + 256];
    dv = gelu_exact(d1) * Wd2[t];
  }
#pragma unroll
  for (int off = 32; off; off >>= 1) dv += __shfl_down(dv, off, 64);
  if (t < DH_SZ && (t & 63) == 0) redd[t >> 6] = dv;
  __syncthreads();

  if (t == 0) {
    float captured = 0.0f;
#pragma unroll
    for (int i = 0; i < 8; ++i) captured += redc[i];
    float d = redd[0] + redd[1] + redd[2] + redd[3] + bd2[0];
    out[b] = captured + d;
  }
}

// ---------------------------------------------------------------------------
extern "C" void kernel_launch(void* const* d_in, const int* in_sizes, int n_in,
                              void* d_out, int out_size, void* d_ws, size_t ws_size,
                              hipStream_t stream) {
  const float* Xg  = (const float*)d_in[0];
  const float* Xl  = (const float*)d_in[1];
  const float* W1  = (const float*)d_in[2];
  const float* b1  = (const float*)d_in[3];
  const float* W2  = (const float*)d_in[4];
  const float* b2  = (const float*)d_in[5];
  const float* wa  = (const float*)d_in[6];
  const float* ba  = (const float*)d_in[7];
  const float* wt  = (const float*)d_in[8];
  const float* bt  = (const float*)d_in[9];
  const float* Wd1 = (const float*)d_in[10];
  const float* bd1 = (const float*)d_in[11];
  const float* Wd2 = (const float*)d_in[12];
  const float* bd2 = (const float*)d_in[13];

  char* ws = (char*)d_ws;
  __bf16* W1p    = (__bf16*)(ws + 0);            //  65536 B
  __bf16* W2p    = (__bf16*)(ws + 65536);        // 524288 B
  float* absorbW = (float*)(ws + 589824);        // 524288 B
  float* attenW  = (float*)(ws + 1114112);       // 524288 B
  float* pooled  = (float*)(ws + 1638400);       // 524288 B  (end 2162688)

  repack_kernel<<<144, 256, 0, stream>>>(W1, W2, W1p, W2p, pooled);
  fused_kernel<<<M_SZ / 64, 1024, 0, stream>>>(Xl, W1p, W2p, b1, b2, wa, ba,
                                               wt, bt, absorbW, attenW, pooled);
  finalize_kernel<<<B_SZ, 512, 0, stream>>>(Xg, absorbW, attenW, pooled,
                                            Wd1, bd1, Wd2, bd2, (float*)d_out);
}